// Round 7
// baseline (388.639 us; speedup 1.0000x reference)
//
#include <hip/hip_runtime.h>
#include <hip/hip_bf16.h>

#define NTOT 1048576
#define NSEG 4096
#define HDIM 128
#define ODIM 256
#define BN   64
#define GRID1 1024
#define TPB  (NTOT / (BN * GRID1))   // 16 tiles per block

typedef __attribute__((ext_vector_type(8))) short bf16x8;
typedef __attribute__((ext_vector_type(4))) float f32x4;
typedef __attribute__((ext_vector_type(2))) unsigned int u32x2;

typedef const __attribute__((address_space(1))) unsigned int* gp_t;
typedef __attribute__((address_space(3))) unsigned int* lp_t;

// HW packed f32->bf16 RNE (no builtin on gfx950; T12 recipe)
__device__ __forceinline__ unsigned int cvt_pk(float lo, float hi) {
    unsigned int r;
    asm("v_cvt_pk_bf16_f32 %0, %1, %2" : "=v"(r) : "v"(lo), "v"(hi));
    return r;
}

// zero sumx (1M floats) + convert W1 (32768 f32 -> 16384 packed u32), one dispatch
__global__ void zero_convert(const float* __restrict__ W1, unsigned int* __restrict__ W1b,
                             float* __restrict__ sumx) {
    int gid = blockIdx.x * 256 + threadIdx.x;
    sumx[gid] = 0.0f;
    if (gid < (ODIM * HDIM / 2)) {
        float2 v = *(const float2*)(W1 + 2 * gid);
        W1b[gid] = cvt_pk(v.x, v.y);
    }
}

// Persistent pipelined stage1, DMA-staged, cvt-once-per-tile:
// iter: {cvt fbuf->bbuf (16 v_cvt_pk/thread)} bar {issue 8 DMAs tile g+1 -> fbuf}
//       {MFMA from bbuf + preloaded W1 frags; tanh; in-reg segreduce} bar(vmcnt0)
__global__ __launch_bounds__(256, 3)
void stage1(const float* __restrict__ x, const int* __restrict__ batch,
            const unsigned short* __restrict__ W1b, const float* __restrict__ b1,
            float* __restrict__ sumx) {
    __shared__ __align__(16) float fbuf[BN * HDIM];          // 32 KB linear f32 tile
    __shared__ __align__(16) unsigned char bbuf[BN * 256];   // 16 KB swizzled bf16 tile
    __shared__ int segAll[TPB * BN];                         // 4 KB

    const int t    = threadIdx.x;
    const int lane = t & 63;
    const int wv   = t >> 6;
    const int l15  = lane & 15;
    const int lhi  = (lane >> 4) & 3;

    // dtype probe: int64 little-endian => odd (high) words are 0
    const bool is64 = (batch[NTOT - 1] == 0);
    const long r0 = (long)blockIdx.x * (TPB * BN);
    const char* xb = (const char*)(x + r0 * HDIM);

    // prologue: DMA tile 0 into fbuf (linear, lane-coalesced 1KB per instr)
    #pragma unroll
    for (int j = 0; j < 8; ++j) {
        const int c0 = j * 256 + wv * 64;    // wave-uniform chunk base
        __builtin_amdgcn_global_load_lds((gp_t)(xb + (size_t)(c0 + lane) * 16),
                                         (lp_t)(fbuf + c0 * 4), 16, 0, 0);
    }

    // while DMA in flight: seg table, W1 B-fragments (64 VGPR, whole kernel), bias
    for (int i = t; i < TPB * BN; i += 256) {
        long idx = r0 + i;
        segAll[i] = batch[is64 ? 2 * idx : idx];
    }
    bf16x8 bfr[4][4];   // [nf][ks]
    #pragma unroll
    for (int nf = 0; nf < 4; ++nf)
        #pragma unroll
        for (int ks = 0; ks < 4; ++ks)
            bfr[nf][ks] = *(const bf16x8*)(W1b + (wv * 64 + nf * 16 + l15) * HDIM + ks * 32 + lhi * 8);
    float bias[4];
    #pragma unroll
    for (int nf = 0; nf < 4; ++nf) bias[nf] = b1[wv * 64 + nf * 16 + l15];

    __syncthreads();    // vmcnt(0): tile 0 landed; segAll visible

    for (int g = 0; g < TPB; ++g) {
        // ---- phase 1: cvt fbuf -> bbuf (swizzled; conflict-free linear reads) ----
        #pragma unroll
        for (int j = 0; j < 8; ++j) {
            const int c = j * 256 + t;
            f32x4 v = ((const f32x4*)fbuf)[c];
            u32x2 p;
            p.x = cvt_pk(v.x, v.y);
            p.y = cvt_pk(v.z, v.w);
            const int row = c >> 5, c4 = c & 31;
            *(u32x2*)(bbuf + row * 256 + ((c4 * 8) ^ ((row & 7) << 4))) = p;
        }
        __syncthreads();          // bbuf complete; fbuf free

        // ---- phase 2: issue DMA prefetch of tile g+1 into fbuf (zero regs) ----
        if (g + 1 < TPB) {
            const char* src = xb + (size_t)(g + 1) * (BN * HDIM * 4);
            #pragma unroll
            for (int j = 0; j < 8; ++j) {
                const int c0 = j * 256 + wv * 64;
                __builtin_amdgcn_global_load_lds((gp_t)(src + (size_t)(c0 + lane) * 16),
                                                 (lp_t)(fbuf + c0 * 4), 16, 0, 0);
            }
        }

        // ---- phase 3: MFMA (no VMEM -> DMA queue untouched) ----
        f32x4 acc[4][4];
        #pragma unroll
        for (int nf = 0; nf < 4; ++nf) {
            const float bb = bias[nf];
            #pragma unroll
            for (int mf = 0; mf < 4; ++mf)
                acc[mf][nf] = (f32x4){bb, bb, bb, bb};
        }
        #pragma unroll
        for (int ks = 0; ks < 4; ++ks) {
            const int k0 = ks * 32 + lhi * 8;
            #pragma unroll
            for (int mf = 0; mf < 4; ++mf) {
                const int m = mf * 16 + l15;
                bf16x8 af = *(const bf16x8*)(bbuf + m * 256 + ((k0 * 2) ^ ((m & 7) << 4)));
                #pragma unroll
                for (int nf = 0; nf < 4; ++nf)
                    acc[mf][nf] = __builtin_amdgcn_mfma_f32_16x16x32_bf16(af, bfr[nf][ks], acc[mf][nf], 0, 0, 0);
            }
        }

        // tanh(s) = 1 - 2/(1 + 2^(s*2*log2e))
        #pragma unroll
        for (int mf = 0; mf < 4; ++mf)
            #pragma unroll
            for (int nf = 0; nf < 4; ++nf)
                #pragma unroll
                for (int r = 0; r < 4; ++r) {
                    float e = exp2f(acc[mf][nf][r] * 2.885390081777927f);
                    acc[mf][nf][r] = 1.0f - 2.0f * __builtin_amdgcn_rcpf(1.0f + e);
                }

        // ---- in-register segmented reduction (batch sorted) ----
        const int* segc = &segAll[g * BN];
        unsigned long long bmask;
        {
            int s_here = segc[lane];
            int s_prev = (lane > 0) ? segc[lane - 1] : s_here;
            bmask = __ballot(s_here != s_prev);
        }
        int start = 0;
        unsigned long long rem = bmask;
        for (;;) {
            const int end = rem ? (int)__builtin_ctzll(rem) : BN;
            const int sid = segc[start];
            float p0 = 0.f, p1 = 0.f, p2 = 0.f, p3 = 0.f;
            #pragma unroll
            for (int mf = 0; mf < 4; ++mf)
                #pragma unroll
                for (int r = 0; r < 4; ++r) {
                    int row = mf * 16 + lhi * 4 + r;
                    float w = ((unsigned)(row - start) < (unsigned)(end - start)) ? 1.0f : 0.0f;
                    p0 = fmaf(w, acc[mf][0][r], p0);
                    p1 = fmaf(w, acc[mf][1][r], p1);
                    p2 = fmaf(w, acc[mf][2][r], p2);
                    p3 = fmaf(w, acc[mf][3][r], p3);
                }
            p0 += __shfl_xor(p0, 16); p0 += __shfl_xor(p0, 32);
            p1 += __shfl_xor(p1, 16); p1 += __shfl_xor(p1, 32);
            p2 += __shfl_xor(p2, 16); p2 += __shfl_xor(p2, 32);
            p3 += __shfl_xor(p3, 16); p3 += __shfl_xor(p3, 32);
            if (lhi == 0) {
                float* base = sumx + (long)sid * ODIM + wv * 64 + l15;
                atomicAdd(base +  0, p0);
                atomicAdd(base + 16, p1);
                atomicAdd(base + 32, p2);
                atomicAdd(base + 48, p3);
            }
            if (rem == 0) break;
            start = end;
            rem &= rem - 1;
        }

        // drains lgkm (bbuf reads done) AND vmcnt(0) (tile g+1 landed in fbuf)
        __syncthreads();
    }
}

// y[g][h] = b2[h] + sum_o sumx[g][o] * W2[h][o]   (fp32, 268 MFLOP)
__global__ __launch_bounds__(256)
void stage2(const float* __restrict__ sumx, const float* __restrict__ W2,
            const float* __restrict__ b2, float* __restrict__ y) {
    __shared__ float sx[16 * 256];
    const int t = threadIdx.x;
    const long g0 = (long)blockIdx.x * 16;
    #pragma unroll
    for (int i = 0; i < 16; ++i)
        sx[i * 256 + t] = sumx[(g0 + i) * 256 + t];
    __syncthreads();
    const int h = t & 127;
    const int gl0 = (t >> 7) * 8;
    float acc[8] = {0, 0, 0, 0, 0, 0, 0, 0};
    const float* w = W2 + h * 256;
    for (int o4 = 0; o4 < 64; ++o4) {
        float4 wvv = *(const float4*)(w + o4 * 4);
        #pragma unroll
        for (int gl = 0; gl < 8; ++gl) {
            const float* sr = &sx[(gl0 + gl) * 256 + o4 * 4];
            acc[gl] += sr[0] * wvv.x + sr[1] * wvv.y + sr[2] * wvv.z + sr[3] * wvv.w;
        }
    }
    float bb = b2[h];
    #pragma unroll
    for (int gl = 0; gl < 8; ++gl)
        y[(g0 + gl0 + gl) * 128 + h] = acc[gl] + bb;
}

extern "C" void kernel_launch(void* const* d_in, const int* in_sizes, int n_in,
                              void* d_out, int out_size, void* d_ws, size_t ws_size,
                              hipStream_t stream) {
    const float* x   = (const float*)d_in[0];
    const int* batch = (const int*)d_in[1];
    const float* W1  = (const float*)d_in[2];
    const float* b1  = (const float*)d_in[3];
    const float* W2  = (const float*)d_in[4];
    const float* b2  = (const float*)d_in[5];
    float* y = (float*)d_out;

    float* sumx = (float*)d_ws;                                                     // 4 MB
    unsigned short* W1b = (unsigned short*)((char*)d_ws + (size_t)NSEG * ODIM * 4); // 64 KB

    zero_convert<<<dim3(NSEG), dim3(256), 0, stream>>>(W1, (unsigned int*)W1b, sumx);
    stage1<<<dim3(GRID1), dim3(256), 0, stream>>>(x, batch, W1b, b1, sumx);
    stage2<<<dim3(NSEG / 16), dim3(256), 0, stream>>>(sumx, W2, b2, y);
}

// Round 8
// 217.937 us; speedup vs baseline: 1.7833x; 1.7833x over previous
//
#include <hip/hip_runtime.h>
#include <hip/hip_bf16.h>

#define NTOT 1048576
#define NSEG 4096
#define HDIM 128
#define ODIM 256
#define BN   64
#define GRID1 1024
#define TPB  (NTOT / (BN * GRID1))   // 16 tiles per block

typedef __attribute__((ext_vector_type(8))) short bf16x8;
typedef __attribute__((ext_vector_type(4))) float f32x4;
typedef __attribute__((ext_vector_type(4))) unsigned int u32x4;

typedef const __attribute__((address_space(1))) unsigned int* gp_t;
typedef __attribute__((address_space(3))) unsigned int* lp_t;

// HW packed f32->bf16 RNE (no builtin on gfx950)
__device__ __forceinline__ unsigned int cvt_pk(float lo, float hi) {
    unsigned int r;
    asm("v_cvt_pk_bf16_f32 %0, %1, %2" : "=v"(r) : "v"(lo), "v"(hi));
    return r;
}

// zero sumx (1M floats) + convert W1 (32768 f32 -> 16384 packed u32), one dispatch
__global__ void zero_convert(const float* __restrict__ W1, unsigned int* __restrict__ W1b,
                             float* __restrict__ sumx) {
    int gid = blockIdx.x * 256 + threadIdx.x;
    sumx[gid] = 0.0f;
    if (gid < (ODIM * HDIM / 2)) {
        float2 v = *(const float2*)(W1 + 2 * gid);
        W1b[gid] = cvt_pk(v.x, v.y);
    }
}

// Persistent DMA-pipelined stage1 with COUNTED vmcnt (T4): the 8 prefetch DMAs
// stay in flight across the barriers; steady loop never drains vmcnt to 0.
// iter g: {issue 8 DMAs g+1 -> buf^1} vmcnt(8) bar1
//         {ds_read f32 frags, cvt_pk, MFMA, tanh, in-reg segreduce+atomics}
//         lgkmcnt(0) bar2
__global__ __launch_bounds__(256, 2)
void stage1(const float* __restrict__ x, const int* __restrict__ batch,
            const unsigned short* __restrict__ W1b, const float* __restrict__ b1,
            float* __restrict__ sumx) {
    // fragment-major f32 tiles (R6 layout, HW-verified): 16B chunk b=ks*8+mf*2+half
    // for lane (l15,lhi) lives at LDS chunk b*64+lane.
    __shared__ __align__(16) float xbuf[2][BN * HDIM];   // 2 x 32 KB
    __shared__ int segAll[TPB * BN];                     // 4 KB

    const int t    = threadIdx.x;
    const int lane = t & 63;
    const int wv   = t >> 6;
    const int l15  = lane & 15;
    const int lhi  = (lane >> 4) & 3;

    // dtype probe: int64 little-endian => odd (high) words are 0
    const bool is64 = (batch[NTOT - 1] == 0);
    const long r0 = (long)blockIdx.x * (TPB * BN);
    const char* xb = (const char*)(x + r0 * HDIM);

    // DMA source byte-offsets within a 32KB tile (pre-permuted global -> fragment-major LDS)
    int doff[8];
    #pragma unroll
    for (int j = 0; j < 8; ++j) {
        int b   = wv * 8 + j;
        int row = ((b >> 1) & 3) * 16 + l15;
        int c4  = (b >> 3) * 8 + lhi * 2 + (b & 1);
        doff[j] = row * 512 + c4 * 16;
    }

    // prologue: start tile-0 DMA first (HBM latency overlaps the staging below)
    #pragma unroll
    for (int j = 0; j < 8; ++j)
        __builtin_amdgcn_global_load_lds((gp_t)(xb + doff[j]),
                                         (lp_t)(&xbuf[0][(wv * 8 + j) * 64 * 4]), 16, 0, 0);
    __builtin_amdgcn_sched_barrier(0);

    // seg table for the whole block; W1 B-fragments + bias preloaded (no VMEM in compute phase)
    for (int i = t; i < TPB * BN; i += 256) {
        long idx = r0 + i;
        segAll[i] = batch[is64 ? 2 * idx : idx];
    }
    bf16x8 bfr[4][4];   // [nf][ks]
    #pragma unroll
    for (int nf = 0; nf < 4; ++nf)
        #pragma unroll
        for (int ks = 0; ks < 4; ++ks)
            bfr[nf][ks] = *(const bf16x8*)(W1b + (wv * 64 + nf * 16 + l15) * HDIM + ks * 32 + lhi * 8);
    float bias[4];
    #pragma unroll
    for (int nf = 0; nf < 4; ++nf) bias[nf] = b1[wv * 64 + nf * 16 + l15];

    // segAll visible + tile0 landed (prologue-only full drain is fine)
    asm volatile("s_waitcnt vmcnt(0) lgkmcnt(0)" ::: "memory");
    __builtin_amdgcn_sched_barrier(0);
    __builtin_amdgcn_s_barrier();

    for (int g = 0; g < TPB; ++g) {
        const int nb = g & 1;

        if (g + 1 < TPB) {
            // issue prefetch DMAs for tile g+1 into the other buffer (freed by bar2 of g-1)
            const char* src = xb + (size_t)(g + 1) * (BN * HDIM * 4);
            #pragma unroll
            for (int j = 0; j < 8; ++j)
                __builtin_amdgcn_global_load_lds((gp_t)(src + doff[j]),
                                                 (lp_t)(&xbuf[nb ^ 1][(wv * 8 + j) * 64 * 4]), 16, 0, 0);
            __builtin_amdgcn_sched_barrier(0);
            // wait all but the 8 just issued: tile g's DMAs + older atomics complete
            asm volatile("s_waitcnt vmcnt(8)" ::: "memory");
        } else {
            asm volatile("s_waitcnt vmcnt(0)" ::: "memory");
        }
        __builtin_amdgcn_sched_barrier(0);
        __builtin_amdgcn_s_barrier();   // bar1: tile g fully in LDS for all waves
        __builtin_amdgcn_sched_barrier(0);

        // ---- compute tile g from xbuf[nb] (pure LDS+VALU+MFMA; no VMEM loads) ----
        f32x4 acc[4][4];
        #pragma unroll
        for (int nf = 0; nf < 4; ++nf) {
            const float bb = bias[nf];
            #pragma unroll
            for (int mf = 0; mf < 4; ++mf)
                acc[mf][nf] = (f32x4){bb, bb, bb, bb};
        }
        const f32x4* fb = (const f32x4*)&xbuf[nb][0];
        #pragma unroll
        for (int ks = 0; ks < 4; ++ks) {
            #pragma unroll
            for (int mf = 0; mf < 4; ++mf) {
                f32x4 u = fb[(ks * 8 + mf * 2) * 64 + lane];         // conflict-free: 64 consecutive lanes
                f32x4 v = fb[(ks * 8 + mf * 2 + 1) * 64 + lane];
                u32x4 w;
                w.x = cvt_pk(u.x, u.y); w.y = cvt_pk(u.z, u.w);
                w.z = cvt_pk(v.x, v.y); w.w = cvt_pk(v.z, v.w);
                bf16x8 af = __builtin_bit_cast(bf16x8, w);
                #pragma unroll
                for (int nf = 0; nf < 4; ++nf)
                    acc[mf][nf] = __builtin_amdgcn_mfma_f32_16x16x32_bf16(af, bfr[nf][ks], acc[mf][nf], 0, 0, 0);
            }
        }

        // tanh(s) = 1 - 2/(1 + 2^(s*2*log2e))
        #pragma unroll
        for (int mf = 0; mf < 4; ++mf)
            #pragma unroll
            for (int nf = 0; nf < 4; ++nf)
                #pragma unroll
                for (int r = 0; r < 4; ++r) {
                    float e = exp2f(acc[mf][nf][r] * 2.885390081777927f);
                    acc[mf][nf][r] = 1.0f - 2.0f * __builtin_amdgcn_rcpf(1.0f + e);
                }

        // in-register segmented reduction (batch sorted); atomics are fire-and-forget
        const int* segc = &segAll[g * BN];
        unsigned long long bmask;
        {
            int s_here = segc[lane];
            int s_prev = (lane > 0) ? segc[lane - 1] : s_here;
            bmask = __ballot(s_here != s_prev);
        }
        int start = 0;
        unsigned long long rem = bmask;
        for (;;) {
            const int end = rem ? (int)__builtin_ctzll(rem) : BN;
            const int sid = segc[start];
            float p0 = 0.f, p1 = 0.f, p2 = 0.f, p3 = 0.f;
            #pragma unroll
            for (int mf = 0; mf < 4; ++mf)
                #pragma unroll
                for (int r = 0; r < 4; ++r) {
                    int row = mf * 16 + lhi * 4 + r;
                    float w = ((unsigned)(row - start) < (unsigned)(end - start)) ? 1.0f : 0.0f;
                    p0 = fmaf(w, acc[mf][0][r], p0);
                    p1 = fmaf(w, acc[mf][1][r], p1);
                    p2 = fmaf(w, acc[mf][2][r], p2);
                    p3 = fmaf(w, acc[mf][3][r], p3);
                }
            p0 += __shfl_xor(p0, 16); p0 += __shfl_xor(p0, 32);
            p1 += __shfl_xor(p1, 16); p1 += __shfl_xor(p1, 32);
            p2 += __shfl_xor(p2, 16); p2 += __shfl_xor(p2, 32);
            p3 += __shfl_xor(p3, 16); p3 += __shfl_xor(p3, 32);
            if (lhi == 0) {
                float* base = sumx + (long)sid * ODIM + wv * 64 + l15;
                atomicAdd(base +  0, p0);
                atomicAdd(base + 16, p1);
                atomicAdd(base + 32, p2);
                atomicAdd(base + 48, p3);
            }
            if (rem == 0) break;
            start = end;
            rem &= rem - 1;
        }

        // bar2: my ds_reads of xbuf[nb] retired -> buffer free for next iter's DMA
        asm volatile("s_waitcnt lgkmcnt(0)" ::: "memory");
        __builtin_amdgcn_sched_barrier(0);
        __builtin_amdgcn_s_barrier();
        __builtin_amdgcn_sched_barrier(0);
    }
}

// y[g][h] = b2[h] + sum_o sumx[g][o] * W2[h][o]   (fp32, 268 MFLOP)
__global__ __launch_bounds__(256)
void stage2(const float* __restrict__ sumx, const float* __restrict__ W2,
            const float* __restrict__ b2, float* __restrict__ y) {
    __shared__ float sx[16 * 256];
    const int t = threadIdx.x;
    const long g0 = (long)blockIdx.x * 16;
    #pragma unroll
    for (int i = 0; i < 16; ++i)
        sx[i * 256 + t] = sumx[(g0 + i) * 256 + t];
    __syncthreads();
    const int h = t & 127;
    const int gl0 = (t >> 7) * 8;
    float acc[8] = {0, 0, 0, 0, 0, 0, 0, 0};
    const float* w = W2 + h * 256;
    for (int o4 = 0; o4 < 64; ++o4) {
        float4 wvv = *(const float4*)(w + o4 * 4);
        #pragma unroll
        for (int gl = 0; gl < 8; ++gl) {
            const float* sr = &sx[(gl0 + gl) * 256 + o4 * 4];
            acc[gl] += sr[0] * wvv.x + sr[1] * wvv.y + sr[2] * wvv.z + sr[3] * wvv.w;
        }
    }
    float bb = b2[h];
    #pragma unroll
    for (int gl = 0; gl < 8; ++gl)
        y[(g0 + gl0 + gl) * 128 + h] = acc[gl] + bb;
}

extern "C" void kernel_launch(void* const* d_in, const int* in_sizes, int n_in,
                              void* d_out, int out_size, void* d_ws, size_t ws_size,
                              hipStream_t stream) {
    const float* x   = (const float*)d_in[0];
    const int* batch = (const int*)d_in[1];
    const float* W1  = (const float*)d_in[2];
    const float* b1  = (const float*)d_in[3];
    const float* W2  = (const float*)d_in[4];
    const float* b2  = (const float*)d_in[5];
    float* y = (float*)d_out;

    float* sumx = (float*)d_ws;                                                     // 4 MB
    unsigned short* W1b = (unsigned short*)((char*)d_ws + (size_t)NSEG * ODIM * 4); // 64 KB

    zero_convert<<<dim3(NSEG), dim3(256), 0, stream>>>(W1, (unsigned int*)W1b, sumx);
    stage1<<<dim3(GRID1), dim3(256), 0, stream>>>(x, batch, W1b, b1, sumx);
    stage2<<<dim3(NSEG / 16), dim3(256), 0, stream>>>(sumx, W2, b2, y);
}